// Round 5
// baseline (459.757 us; speedup 1.0000x reference)
//
#include <hip/hip_runtime.h>

// GraphAttentionLayer: B=16, N=2048, F_IN=256, H=128 (fp32 in/out, adj int32)
//  k_wh  : MFMA bf16x3-split GEMM wh = X@W^T + bW; fused src/dst dots + bf16
//          transposed wh_T out
//  k_attn: unnormalized-softmax MFMA attention, HBM-streaming on adj.
//          TI=32 x TJ=128 tiles, 1024 blocks, adj register-prefetch.

#define BDIM 16
#define NDIM 2048
#define FIN 256
#define HDIM 128

typedef short short8 __attribute__((ext_vector_type(8)));
typedef float floatx4 __attribute__((ext_vector_type(4)));

__device__ __forceinline__ unsigned short f2bf(float x) {
    unsigned int u = __float_as_uint(x);
    unsigned int r = (u + 0x7fffu + ((u >> 16) & 1u)) >> 16;  // RNE
    return (unsigned short)r;
}
__device__ __forceinline__ float bf2f(unsigned short s) {
    return __uint_as_float(((unsigned int)s) << 16);
}

// ---------------- Kernel 1: wh via MFMA (bf16 hi/lo split) ----------------
__global__ __launch_bounds__(256) void k_wh(const float* __restrict__ X,
                                            const float* __restrict__ W,
                                            const float* __restrict__ bW,
                                            const float* __restrict__ a,
                                            float* __restrict__ src,
                                            float* __restrict__ dst,
                                            unsigned short* __restrict__ whbT) {
    __shared__ short lds[27648];                    // 54 KB
    short (*ah)[72] = (short(*)[72])lds;
    short (*al)[72] = (short(*)[72])(lds + 4608);
    short (*bh)[72] = (short(*)[72])(lds + 9216);
    short (*bl)[72] = (short(*)[72])(lds + 18432);
    short (*tb)[72] = (short(*)[72])lds;            // epilogue alias

    const int tid = threadIdx.x;
    const long row0 = (long)blockIdx.x * 64;
    const int w = tid >> 6, lane = tid & 63;
    const int lm = lane & 15, q = lane >> 4;

    float a1v[8], a2v[8], bwv[8];
    #pragma unroll
    for (int nt = 0; nt < 8; nt++) {
        a1v[nt] = a[nt * 16 + lm];
        a2v[nt] = a[HDIM + nt * 16 + lm];
        bwv[nt] = bW[nt * 16 + lm];
    }

    floatx4 acc[8];
    #pragma unroll
    for (int nt = 0; nt < 8; nt++) acc[nt] = (floatx4){0.f, 0.f, 0.f, 0.f};

    for (int k0 = 0; k0 < FIN; k0 += 64) {
        #pragma unroll
        for (int u = 0; u < 4; u++) {
            int idx = tid + u * 256;
            int r = idx >> 4, fc = (idx & 15) * 4;
            float4 v = *reinterpret_cast<const float4*>(X + (row0 + r) * FIN + k0 + fc);
            union { unsigned short s[4]; uint2 u2; } ph, pl;
            ph.s[0] = f2bf(v.x); pl.s[0] = f2bf(v.x - bf2f(ph.s[0]));
            ph.s[1] = f2bf(v.y); pl.s[1] = f2bf(v.y - bf2f(ph.s[1]));
            ph.s[2] = f2bf(v.z); pl.s[2] = f2bf(v.z - bf2f(ph.s[2]));
            ph.s[3] = f2bf(v.w); pl.s[3] = f2bf(v.w - bf2f(ph.s[3]));
            *reinterpret_cast<uint2*>(&ah[r][fc]) = ph.u2;
            *reinterpret_cast<uint2*>(&al[r][fc]) = pl.u2;
        }
        #pragma unroll
        for (int u = 0; u < 8; u++) {
            int idx = tid + u * 256;
            int hh = idx >> 4, fc = (idx & 15) * 4;
            float4 v = *reinterpret_cast<const float4*>(W + hh * FIN + k0 + fc);
            union { unsigned short s[4]; uint2 u2; } ph, pl;
            ph.s[0] = f2bf(v.x); pl.s[0] = f2bf(v.x - bf2f(ph.s[0]));
            ph.s[1] = f2bf(v.y); pl.s[1] = f2bf(v.y - bf2f(ph.s[1]));
            ph.s[2] = f2bf(v.z); pl.s[2] = f2bf(v.z - bf2f(ph.s[2]));
            ph.s[3] = f2bf(v.w); pl.s[3] = f2bf(v.w - bf2f(ph.s[3]));
            *reinterpret_cast<uint2*>(&bh[hh][fc]) = ph.u2;
            *reinterpret_cast<uint2*>(&bl[hh][fc]) = pl.u2;
        }
        __syncthreads();
        #pragma unroll
        for (int ks = 0; ks < 64; ks += 32) {
            short8 afh = *reinterpret_cast<const short8*>(&ah[w * 16 + lm][ks + q * 8]);
            short8 afl = *reinterpret_cast<const short8*>(&al[w * 16 + lm][ks + q * 8]);
            #pragma unroll
            for (int nt = 0; nt < 8; nt++) {
                short8 bfh = *reinterpret_cast<const short8*>(&bh[nt * 16 + lm][ks + q * 8]);
                short8 bfl = *reinterpret_cast<const short8*>(&bl[nt * 16 + lm][ks + q * 8]);
                acc[nt] = __builtin_amdgcn_mfma_f32_16x16x32_bf16(afh, bfh, acc[nt], 0, 0, 0);
                acc[nt] = __builtin_amdgcn_mfma_f32_16x16x32_bf16(afh, bfl, acc[nt], 0, 0, 0);
                acc[nt] = __builtin_amdgcn_mfma_f32_16x16x32_bf16(afl, bfh, acc[nt], 0, 0, 0);
            }
        }
        __syncthreads();
    }

    float s1[4] = {0.f, 0.f, 0.f, 0.f}, s2[4] = {0.f, 0.f, 0.f, 0.f};
    #pragma unroll
    for (int nt = 0; nt < 8; nt++) {
        #pragma unroll
        for (int r = 0; r < 4; r++) {
            float v = acc[nt][r] + bwv[nt];
            s1[r] += v * a1v[nt];
            s2[r] += v * a2v[nt];
            tb[nt * 16 + lm][w * 16 + q * 4 + r] = f2bf(v);
        }
    }
    #pragma unroll
    for (int r = 0; r < 4; r++) {
        #pragma unroll
        for (int o = 1; o < 16; o <<= 1) {
            s1[r] += __shfl_xor(s1[r], o);
            s2[r] += __shfl_xor(s2[r], o);
        }
    }
    if (lm == 0) {
        #pragma unroll
        for (int r = 0; r < 4; r++) {
            long row = row0 + w * 16 + q * 4 + r;
            src[row] = s1[r];
            dst[row] = s2[r];
        }
    }
    __syncthreads();
    const int b = (int)(row0 >> 11);
    const int n0 = (int)(row0 & 2047);
    #pragma unroll
    for (int u = 0; u < 4; u++) {
        int idx = tid + u * 256;
        int hh = idx >> 3, c = idx & 7;
        *reinterpret_cast<uint4*>(whbT + ((size_t)(b * HDIM + hh)) * NDIM + n0 + c * 8) =
            *reinterpret_cast<const uint4*>(&tb[hh][c * 8]);
    }
}

// ---------------- Kernel 2: streaming MFMA attention ----------------
#define TI 32
#define TJ 128
#define LDP 136   // padded bf16 row: stride 68 dwords -> conflict-free b128 frags

__global__ __launch_bounds__(256) void k_attn(const int* __restrict__ adj,
                                              const unsigned short* __restrict__ whbT,
                                              const float* __restrict__ src,
                                              const float* __restrict__ dst,
                                              const float* __restrict__ ba_p,
                                              float* __restrict__ out) {
    __shared__ unsigned short whsT[HDIM][LDP];   // 34.8 KB [h][j] bf16
    __shared__ unsigned short wt[TI][LDP];       // 8.7 KB  [i][j] bf16
    __shared__ float s_src[TI];
    __shared__ float lred[TI];
    __shared__ float linv_s[TI];

    const int tid = threadIdx.x;
    const int b = blockIdx.x >> 6;            // 64 i-tiles per batch
    const int i0 = (blockIdx.x & 63) * TI;

    if (tid < TI) s_src[tid] = src[b * NDIM + i0 + tid] + ba_p[0];
    __syncthreads();

    const int wave = tid >> 6, lane = tid & 63;
    const int lm = lane & 15, q = lane >> 4;
    const int ib = (wave & 1) * 16;
    const int hb = (wave >> 1) * 64;
    const int wtrow = tid >> 3, wtg = tid & 7;   // row 0..31, j-group of 16

    const float* dstb = dst + b * NDIM;
    const unsigned short* whb = whbT + (size_t)b * HDIM * NDIM;
    const int* adjp = adj + ((long)(b * NDIM + i0 + wtrow)) * NDIM + wtg * 16;
    const float si = s_src[wtrow];

    floatx4 acc[4];
    #pragma unroll
    for (int hj = 0; hj < 4; hj++) acc[hj] = (floatx4){0.f, 0.f, 0.f, 0.f};
    float lpart = 0.f;

    // prefetch adj tile 0
    int4 na[4];
    #pragma unroll
    for (int p = 0; p < 4; p++) na[p] = *reinterpret_cast<const int4*>(adjp + p * 4);

    for (int t = 0; t < NDIM / TJ; t++) {
        const int j0 = t * TJ;
        // stage whsT tile [128h][128j]
        #pragma unroll
        for (int u = 0; u < 8; u++) {
            int idx = tid + u * 256;
            int hh = idx >> 4, c = idx & 15;
            *reinterpret_cast<uint4*>(&whsT[hh][c * 8]) =
                *reinterpret_cast<const uint4*>(whb + (size_t)hh * NDIM + j0 + c * 8);
        }
        // weight tile from prefetched adj
        {
            const float* dq = dstb + j0 + wtg * 16;
            unsigned short wbf[16];
            #pragma unroll
            for (int p = 0; p < 4; p++) {
                float4 dv = *reinterpret_cast<const float4*>(dq + p * 4);
                float x0 = si + dv.x, x1 = si + dv.y, x2 = si + dv.z, x3 = si + dv.w;
                x0 = x0 > 0.f ? x0 : 0.01f * x0;
                x1 = x1 > 0.f ? x1 : 0.01f * x1;
                x2 = x2 > 0.f ? x2 : 0.01f * x2;
                x3 = x3 > 0.f ? x3 : 0.01f * x3;
                float w0 = na[p].x > 0 ? __expf(x0) : 0.f;
                float w1 = na[p].y > 0 ? __expf(x1) : 0.f;
                float w2 = na[p].z > 0 ? __expf(x2) : 0.f;
                float w3 = na[p].w > 0 ? __expf(x3) : 0.f;
                lpart += (w0 + w1) + (w2 + w3);
                wbf[4 * p + 0] = f2bf(w0); wbf[4 * p + 1] = f2bf(w1);
                wbf[4 * p + 2] = f2bf(w2); wbf[4 * p + 3] = f2bf(w3);
            }
            *reinterpret_cast<uint4*>(&wt[wtrow][wtg * 16]) =
                *reinterpret_cast<const uint4*>(&wbf[0]);
            *reinterpret_cast<uint4*>(&wt[wtrow][wtg * 16 + 8]) =
                *reinterpret_cast<const uint4*>(&wbf[8]);
        }
        __syncthreads();
        // prefetch next adj tile (overlaps MFMA + next exp phase across blocks)
        if (t + 1 < NDIM / TJ) {
            adjp += TJ;
            #pragma unroll
            for (int p = 0; p < 4; p++) na[p] = *reinterpret_cast<const int4*>(adjp + p * 4);
        }
        // MFMA
        #pragma unroll
        for (int k0 = 0; k0 < TJ; k0 += 32) {
            short8 af = *reinterpret_cast<const short8*>(&wt[ib + lm][k0 + q * 8]);
            #pragma unroll
            for (int hj = 0; hj < 4; hj++) {
                short8 bfr = *reinterpret_cast<const short8*>(&whsT[hb + hj * 16 + lm][k0 + q * 8]);
                acc[hj] = __builtin_amdgcn_mfma_f32_16x16x32_bf16(af, bfr, acc[hj], 0, 0, 0);
            }
        }
        __syncthreads();
    }

    // row-sum reduction (8 consecutive lanes per row, same wave)
    lpart += __shfl_xor(lpart, 1);
    lpart += __shfl_xor(lpart, 2);
    lpart += __shfl_xor(lpart, 4);
    if (wtg == 0) lred[wtrow] = lpart;
    __syncthreads();
    if (tid < TI) {
        float l = lred[tid];
        linv_s[tid] = l > 0.f ? 1.f / l : 0.f;
    }
    __syncthreads();

    // epilogue: scale by 1/l, ELU, store (C/D: col=lm, row=q*4+r)
    #pragma unroll
    for (int r = 0; r < 4; r++) {
        int il = ib + q * 4 + r;
        float li = linv_s[il];
        long obase = ((long)(b * NDIM + i0 + il)) * HDIM + hb + lm;
        #pragma unroll
        for (int hj = 0; hj < 4; hj++) {
            float x = acc[hj][r] * li;
            x = x > 0.f ? x : (__expf(x) - 1.f);
            out[obase + hj * 16] = x;
        }
    }
}

extern "C" void kernel_launch(void* const* d_in, const int* in_sizes, int n_in,
                              void* d_out, int out_size, void* d_ws, size_t ws_size,
                              hipStream_t stream) {
    const float* X  = (const float*)d_in[0];   // [16,2048,256]
    const int* adj  = (const int*)d_in[1];     // [16,2048,2048]
    const float* W  = (const float*)d_in[2];   // [128,256]
    const float* bW = (const float*)d_in[3];   // [128]
    const float* a  = (const float*)d_in[4];   // [1,256]
    const float* ba = (const float*)d_in[5];   // [1]
    float* out = (float*)d_out;                // [16,2048,128]

    float* srcv = (float*)d_ws;                        // B*N
    float* dstv = srcv + BDIM * NDIM;                  // B*N
    unsigned short* whbT = (unsigned short*)(dstv + BDIM * NDIM);  // B*H*N bf16 (8 MB)

    k_wh<<<BDIM * NDIM / 64, 256, 0, stream>>>(X, W, bW, a, srcv, dstv, whbT);
    k_attn<<<BDIM * (NDIM / TI), 256, 0, stream>>>(adj, whbT, srcv, dstv, ba, out);
}